// Round 13
// baseline (363.928 us; speedup 1.0000x reference)
//
#include <hip/hip_runtime.h>
#include <hip/hip_bf16.h>

#define NN 207
#define DD 128
#define LL 4
#define BB 16
#define ROWS (BB*NN)   // 3312
#define RB 8
#define LBLK (ROWS/RB) // 414
#define EPSV 1e-5f
#define SLOPE 0.2f
#define GT4B (32*208*4) // floats per batch in packed-transposed gs

#define BFBITS 0x3F803F80u

// ---------- dtype-flexible load ----------
template<bool BF>
__device__ __forceinline__ float ldin(const void* p, int i) {
    if (BF) {
        unsigned short u = ((const unsigned short*)p)[i];
        return __uint_as_float(((unsigned)u) << 16);
    } else {
        return ((const float*)p)[i];
    }
}

// load float4 worth (4 elems) at float4-index q from a (possibly bf16) array
template<bool BF>
__device__ __forceinline__ float4 ld4(const void* p, int q4) {
    if (BF) {
        uint2 u = ((const uint2*)p)[q4];
        float4 r;
        r.x = __uint_as_float(u.x << 16);
        r.y = __uint_as_float(u.x & 0xFFFF0000u);
        r.z = __uint_as_float(u.y << 16);
        r.w = __uint_as_float(u.y & 0xFFFF0000u);
        return r;
    } else {
        return ((const float4*)p)[q4];
    }
}

// load 32 consecutive weight elements (base multiple of 8) into f32 regs
template<bool BF>
__device__ __forceinline__ void ldw32(const void* W, int base, float* w) {
    if (BF) {
        const uint4* p = (const uint4*)((const unsigned short*)W + base);
#pragma unroll
        for (int q = 0; q < 4; q++) {
            uint4 u = p[q];
            w[q*8+0] = __uint_as_float(u.x << 16);
            w[q*8+1] = __uint_as_float(u.x & 0xFFFF0000u);
            w[q*8+2] = __uint_as_float(u.y << 16);
            w[q*8+3] = __uint_as_float(u.y & 0xFFFF0000u);
            w[q*8+4] = __uint_as_float(u.z << 16);
            w[q*8+5] = __uint_as_float(u.z & 0xFFFF0000u);
            w[q*8+6] = __uint_as_float(u.w << 16);
            w[q*8+7] = __uint_as_float(u.w & 0xFFFF0000u);
        }
    } else {
        const float4* p = (const float4*)((const float*)W + base);
#pragma unroll
        for (int q = 0; q < 8; q++) {
            float4 u = p[q];
            w[q*4+0] = u.x; w[q*4+1] = u.y; w[q*4+2] = u.z; w[q*4+3] = u.w;
        }
    }
}

// dot of one weight row with sh[0..127] (k_et only)
template<bool BF>
__device__ __forceinline__ float rowdot(const void* W, int rowbase, const float* sh) {
    float acc = 0.f;
    if (BF) {
        const uint4* p = (const uint4*)((const unsigned short*)W + rowbase);
#pragma unroll
        for (int q = 0; q < DD / 8; q++) {
            uint4 u = p[q];
            const float* s = sh + q * 8;
            acc += __uint_as_float(u.x << 16)        * s[0];
            acc += __uint_as_float(u.x & 0xFFFF0000u) * s[1];
            acc += __uint_as_float(u.y << 16)        * s[2];
            acc += __uint_as_float(u.y & 0xFFFF0000u) * s[3];
            acc += __uint_as_float(u.z << 16)        * s[4];
            acc += __uint_as_float(u.z & 0xFFFF0000u) * s[5];
            acc += __uint_as_float(u.w << 16)        * s[6];
            acc += __uint_as_float(u.w & 0xFFFF0000u) * s[7];
        }
    } else {
        const float4* p = (const float4*)((const float*)W + rowbase);
#pragma unroll
        for (int q = 0; q < DD / 4; q++) {
            float4 u = p[q];
            const float* s = sh + q * 4;
            acc += u.x * s[0]; acc += u.y * s[1]; acc += u.z * s[2]; acc += u.w * s[3];
        }
    }
    return acc;
}

// ---------- edge tables: et[l][c12][d] ----------
template<bool BF>
__device__ void et_body(float* sh, const void* emb, const void* We, float* et) {
    int l = blockIdx.x / 12, c = blockIdx.x % 12, d = threadIdx.x;
    sh[d] = ldin<BF>(emb, c * DD + d);
    __syncthreads();
    et[(l * 12 + c) * DD + d] = rowdot<BF>(We, l * DD * DD + d * DD, sh);
}
__global__ void k_et(const unsigned* bits, const void* emb, const void* We, float* et) {
    __shared__ __align__(16) float smem[DD];
    if (bits[0] == BFBITS) et_body<true>(smem, emb, We, et);
    else                   et_body<false>(smem, emb, We, et);
}

// ---------- mlp1: Linear(6->D) -> LN -> ReLU -> tmp ----------
template<bool BF>
__device__ void mlp1_body(float* smem, const void* x, const void* W1, const void* b1,
                          const void* g1, const void* bv1, float* tmp) {
    float* s_x   = smem;                 // 48
    float* so    = s_x + 48;             // RB*132
    float* stats = so + RB * 132;        // RB*2
    int r0 = blockIdx.x * RB, d = threadIdx.x;
    if (d < RB * 6) s_x[d] = ldin<BF>(x, r0 * 6 + d);
    __syncthreads();
    float w6[6];
#pragma unroll
    for (int k = 0; k < 6; k++) w6[k] = ldin<BF>(W1, d * 6 + k);
    float b0 = ldin<BF>(b1, d);
#pragma unroll
    for (int rr = 0; rr < RB; rr++) {
        float a = b0;
#pragma unroll
        for (int k = 0; k < 6; k++) a += w6[k] * s_x[rr * 6 + k];
        so[rr * 132 + d] = a;
    }
    __syncthreads();
    int rr2 = d >> 4, l16 = d & 15;
    float s = 0.f, sq = 0.f;
#pragma unroll
    for (int k = 0; k < 8; k++) { float v = so[rr2 * 132 + l16 + 16 * k]; s += v; sq += v * v; }
    s += __shfl_xor(s, 1); s += __shfl_xor(s, 2); s += __shfl_xor(s, 4); s += __shfl_xor(s, 8);
    sq += __shfl_xor(sq, 1); sq += __shfl_xor(sq, 2); sq += __shfl_xor(sq, 4); sq += __shfl_xor(sq, 8);
    if (l16 == 0) {
        float mean = s * (1.f / DD);
        float var = sq * (1.f / DD) - mean * mean;
        stats[rr2 * 2] = mean; stats[rr2 * 2 + 1] = rsqrtf(var + EPSV);
    }
    __syncthreads();
    float gv = ldin<BF>(g1, d), bb = ldin<BF>(bv1, d);
#pragma unroll
    for (int rr = 0; rr < RB; rr++) {
        float v = (so[rr * 132 + d] - stats[rr * 2]) * stats[rr * 2 + 1] * gv + bb;
        tmp[(r0 + rr) * DD + d] = fmaxf(v, 0.f);
    }
}
__global__ void k_mlp1(const unsigned* bits, const void* x, const void* W1, const void* b1,
                       const void* g1, const void* bv1, float* tmp) {
    __shared__ __align__(16) float smem[48 + RB * 132 + RB * 2];
    if (bits[0] == BFBITS) mlp1_body<true>(smem, x, W1, b1, g1, bv1, tmp);
    else                   mlp1_body<false>(smem, x, W1, b1, g1, bv1, tmp);
}

// ---------- fused: linear + LN (+ReLU+res) -> h, then next gs/gd/gs_t4 OR output head ----------
// smem: sh[RB*DD] (h_new) | so[RB*132] | stats[16] | s_gs[RB*128]
#define LING_SMEM (RB*DD + RB*132 + 16 + RB*128)
template<bool BF>
__device__ void linG_body(float* smem, int epi, int hasNext,
                          const float* __restrict__ in, const void* W, int wOff,
                          const void* bias, const void* g, const void* bv, int dOff,
                          const void* Wl, const void* bl, const void* Wr, const void* br,
                          int nwOff, int nbOff,
                          float* __restrict__ h, float* __restrict__ gs,
                          float* __restrict__ gd, float* __restrict__ gs_t4,
                          const void* oW, const void* ob, void* out) {
    float* sh    = smem;
    float* so    = sh + RB * DD;
    float* stats = so + RB * 132;
    float* s_gs  = stats + 16;
    int r0 = blockIdx.x * RB;
    int t = threadIdx.x, d = t & 127, half = t >> 7;
    // ---- phase A: projection linear; input rows read from GLOBAL (wave-uniform -> scalar) ----
    const float* inr = in + (size_t)r0 * DD + half * 4 * DD;
    float acc[4];
    float b0 = ldin<BF>(bias, dOff + d);
#pragma unroll
    for (int rr = 0; rr < 4; rr++) acc[rr] = b0;
#pragma unroll
    for (int c = 0; c < 4; c++) {
        float w[32];
        ldw32<BF>(W, wOff + d * DD + c * 32, w);
#pragma unroll
        for (int rr = 0; rr < 4; rr++) {
            const float* s = inr + rr * DD + c * 32;
            float a = acc[rr];
#pragma unroll
            for (int k = 0; k < 32; k++) a += s[k] * w[k];
            acc[rr] = a;
        }
    }
#pragma unroll
    for (int rr = 0; rr < 4; rr++) so[(half * 4 + rr) * 132 + d] = acc[rr];
    __syncthreads();
    // ---- LN stats (8 rows x 32 lanes) ----
    int rr2 = t >> 5, l32 = t & 31;
    float s = 0.f, sq = 0.f;
#pragma unroll
    for (int k = 0; k < 4; k++) { float v = so[rr2 * 132 + l32 + 32 * k]; s += v; sq += v * v; }
    s += __shfl_xor(s, 1); s += __shfl_xor(s, 2); s += __shfl_xor(s, 4);
    s += __shfl_xor(s, 8); s += __shfl_xor(s, 16);
    sq += __shfl_xor(sq, 1); sq += __shfl_xor(sq, 2); sq += __shfl_xor(sq, 4);
    sq += __shfl_xor(sq, 8); sq += __shfl_xor(sq, 16);
    if (l32 == 0) {
        float mean = s * (1.f / DD);
        float var = sq * (1.f / DD) - mean * mean;
        stats[rr2 * 2] = mean; stats[rr2 * 2 + 1] = rsqrtf(var + EPSV);
    }
    __syncthreads();
    // ---- epilogue: h_new -> global h AND into sh ----
    float gv = ldin<BF>(g, dOff + d), bb = ldin<BF>(bv, dOff + d);
#pragma unroll
    for (int rr = 0; rr < 4; rr++) {
        int row = half * 4 + rr;
        int rg = r0 + row;
        float v = (so[row * 132 + d] - stats[row * 2]) * stats[row * 2 + 1] * gv + bb;
        float hn;
        if (epi) hn = h[(size_t)rg * DD + d] + fmaxf(v, 0.f);
        else     hn = v;
        h[(size_t)rg * DD + d] = hn;
        sh[row * DD + d] = hn;
    }
    __syncthreads();
    if (!hasNext) {
        // ---- output head ----
        float s0 = 0.f, s1 = 0.f;
#pragma unroll
        for (int k = 0; k < 4; k++) {
            int dd = l32 + 32 * k;
            float hv = sh[rr2 * DD + dd];
            s0 += hv * ldin<BF>(oW, dd);
            s1 += hv * ldin<BF>(oW, DD + dd);
        }
        s0 += __shfl_xor(s0, 1); s0 += __shfl_xor(s0, 2); s0 += __shfl_xor(s0, 4);
        s0 += __shfl_xor(s0, 8); s0 += __shfl_xor(s0, 16);
        s1 += __shfl_xor(s1, 1); s1 += __shfl_xor(s1, 2); s1 += __shfl_xor(s1, 4);
        s1 += __shfl_xor(s1, 8); s1 += __shfl_xor(s1, 16);
        if (l32 == 0) {
            int rg = r0 + rr2;
            float v0 = s0 + ldin<BF>(ob, 0);
            float v1 = s1 + ldin<BF>(ob, 1);
            if (BF) {
                ((__hip_bfloat16*)out)[rg * 2 + 0] = __float2bfloat16(v0);
                ((__hip_bfloat16*)out)[rg * 2 + 1] = __float2bfloat16(v1);
            } else {
                ((float*)out)[rg * 2 + 0] = v0;
                ((float*)out)[rg * 2 + 1] = v1;
            }
        }
        return;
    }
    // ---- phase B: gs/gd for next layer from sh (half -> Wl/Wr) ----
    {
        const void* Wm = half ? Wr : Wl;
        const void* bm = half ? br : bl;
        float acc2[RB];
        float bn = ldin<BF>(bm, nbOff + d);
#pragma unroll
        for (int rr = 0; rr < RB; rr++) acc2[rr] = bn;
#pragma unroll
        for (int c = 0; c < 4; c++) {
            float w[32];
            ldw32<BF>(Wm, nwOff + d * DD + c * 32, w);
#pragma unroll
            for (int rr = 0; rr < RB; rr++) {
                const float* s = sh + rr * DD + c * 32;
                float a = acc2[rr];
#pragma unroll
                for (int k = 0; k < 32; k++) a += s[k] * w[k];
                acc2[rr] = a;
            }
        }
        if (half) {
#pragma unroll
            for (int rr = 0; rr < RB; rr++) gd[(size_t)(r0 + rr) * DD + d] = acc2[rr];
        } else {
#pragma unroll
            for (int rr = 0; rr < RB; rr++) {
                gs[(size_t)(r0 + rr) * DD + d] = acc2[rr];
                s_gs[rr * DD + d] = acc2[rr];
            }
        }
    }
    __syncthreads();
    // ---- gs_t4 write via LDS transpose: lane -> (d4 = t>>3, iL = t&7), i-contiguous ----
    {
        int d4 = t >> 3, iL = t & 7;
        int rg = r0 + iL;
        int bb2 = rg / NN, ii = rg - bb2 * NN;
        float4 v;
        v.x = s_gs[iL * DD + d4 * 4 + 0];
        v.y = s_gs[iL * DD + d4 * 4 + 1];
        v.z = s_gs[iL * DD + d4 * 4 + 2];
        v.w = s_gs[iL * DD + d4 * 4 + 3];
        ((float4*)(gs_t4 + (size_t)bb2 * GT4B))[d4 * 208 + ii] = v;
    }
}
__global__ void k_linG(const unsigned* bits, int epi, int hasNext,
                       const float* in, const void* W, int wOff,
                       const void* bias, const void* g, const void* bv, int dOff,
                       const void* Wl, const void* bl, const void* Wr, const void* br,
                       int nwOff, int nbOff,
                       float* h, float* gs, float* gd, float* gs_t4,
                       const void* oW, const void* ob, void* out) {
    __shared__ __align__(16) float smem[LING_SMEM];
    if (bits[0] == BFBITS)
        linG_body<true>(smem, epi, hasNext, in, W, wOff, bias, g, bv, dOff,
                        Wl, bl, Wr, br, nwOff, nbOff, h, gs, gd, gs_t4, oW, ob, out);
    else
        linG_body<false>(smem, epi, hasNext, in, W, wOff, bias, g, bv, dOff,
                         Wl, bl, Wr, br, nwOff, nbOff, h, gs, gd, gs_t4, oW, ob, out);
}

// ---------- fused attention (1 target per block, 256 thr, XCD-swizzled) ----------
// smem floats: s_ge 12*132 | s_pe 8*212 | s_inv 8 | s_part 128 | s_cat 207
#define ATTN_SMEM (12*132 + 8*212 + 8 + 128 + 207)
template<bool BF>
__device__ void attn_body(float* smem, int l, const float* __restrict__ gs,
                          const float* __restrict__ gd, const float* __restrict__ et,
                          const float* __restrict__ gs_t4, const int* __restrict__ cat,
                          const void* att, const void* cb, float* __restrict__ o) {
    float* s_ge   = smem;                  // 1584
    float* s_pe   = s_ge + 12 * 132;       // 1696
    float* s_inv  = s_pe + 8 * 212;        // 8
    float* s_part = s_inv + 8;             // 128
    int*   s_cat  = (int*)(s_part + 128);  // 207
    int p = blockIdx.x;
    int r = (p & 7) * (ROWS / 8) + (p >> 3);
    int t = threadIdx.x, d = t & 127, seg = t >> 7;
    int b = r / NN, j = r - b * NN;
    for (int idx = t; idx < NN; idx += 256) s_cat[idx] = cat[idx * NN + j];
    for (int idx = t; idx < 12 * DD; idx += 256) {
        int c = idx >> 7, k = idx & 127;
        s_ge[c * 132 + k] = et[l * 12 * DD + idx] + gd[(size_t)r * DD + k];
    }
    __syncthreads();
    const float* gsb = gs + (size_t)b * NN * DD;
    // phase 1: one source per thread; att read from GLOBAL (uniform -> scalar cache)
    if (t < NN) {
        const float4* gt = ((const float4*)(gs_t4 + (size_t)b * GT4B)) + t;
        const float4* ge = (const float4*)(s_ge + s_cat[t] * 132);
        float acc[8];
#pragma unroll
        for (int hh = 0; hh < 8; hh++) acc[hh] = 0.f;
#pragma unroll
        for (int q = 0; q < 32; q++) {
            float4 g4 = gt[q * 208];
            float4 e4 = ge[q];
            float4 a4 = ld4<BF>(att, l * 32 + q);
            float z0 = g4.x + e4.x, z1 = g4.y + e4.y, z2 = g4.z + e4.z, z3 = g4.w + e4.w;
            z0 = fmaxf(z0, SLOPE * z0); z1 = fmaxf(z1, SLOPE * z1);
            z2 = fmaxf(z2, SLOPE * z2); z3 = fmaxf(z3, SLOPE * z3);
            acc[q >> 2] += a4.x * z0 + a4.y * z1 + a4.z * z2 + a4.w * z3;
        }
#pragma unroll
        for (int hh = 0; hh < 8; hh++) s_pe[hh * 212 + t] = acc[hh];
    }
    __syncthreads();
    // phase 2: per-head softmax (threads 0..127)
    if (t < 128) {
        int hh = t >> 4, l16 = t & 15;
        float vals[13]; float mx = -1e30f;
#pragma unroll
        for (int k = 0; k < 13; k++) {
            int i = l16 + 16 * k;
            vals[k] = (i < NN) ? s_pe[hh * 212 + i] : -1e30f;
            mx = fmaxf(mx, vals[k]);
        }
        mx = fmaxf(mx, __shfl_xor(mx, 1)); mx = fmaxf(mx, __shfl_xor(mx, 2));
        mx = fmaxf(mx, __shfl_xor(mx, 4)); mx = fmaxf(mx, __shfl_xor(mx, 8));
        float sum = 0.f;
#pragma unroll
        for (int k = 0; k < 13; k++) {
            int i = l16 + 16 * k;
            float e = (i < NN) ? __expf(vals[k] - mx) : 0.f;
            if (i < 208) s_pe[hh * 212 + i] = e;
            sum += e;
        }
        sum += __shfl_xor(sum, 1); sum += __shfl_xor(sum, 2);
        sum += __shfl_xor(sum, 4); sum += __shfl_xor(sum, 8);
        if (l16 == 0) s_inv[hh] = 1.f / sum;
    }
    __syncthreads();
    // phase 3: o[d] = sum_i e[h(d)][i] * gs[b][i][d], i-range split across seg
    {
        int hh = d >> 4;
        const float* ep = s_pe + hh * 212;
        const float* gp = gsb + d;
        float a0 = 0.f, a1 = 0.f, a2 = 0.f, a3 = 0.f;
        int i = seg * 104;
        int iend = seg ? NN : 104;
        for (; i + 8 <= iend; i += 8) {
            float g0 = gp[(i+0)*DD], g1 = gp[(i+1)*DD], g2 = gp[(i+2)*DD], g3 = gp[(i+3)*DD];
            float g4 = gp[(i+4)*DD], g5 = gp[(i+5)*DD], g6 = gp[(i+6)*DD], g7 = gp[(i+7)*DD];
            a0 = fmaf(ep[i+0], g0, a0); a1 = fmaf(ep[i+1], g1, a1);
            a2 = fmaf(ep[i+2], g2, a2); a3 = fmaf(ep[i+3], g3, a3);
            a0 = fmaf(ep[i+4], g4, a0); a1 = fmaf(ep[i+5], g5, a1);
            a2 = fmaf(ep[i+6], g6, a2); a3 = fmaf(ep[i+7], g7, a3);
        }
        for (; i < iend; i++) a0 = fmaf(ep[i], gp[i * DD], a0);
        float part = a0 + a1 + a2 + a3;
        if (seg) s_part[d] = part;
        __syncthreads();
        if (!seg) o[(size_t)r * DD + d] = (part + s_part[d]) * s_inv[hh] + ldin<BF>(cb, l * DD + d);
    }
}
__global__ void __launch_bounds__(256, 4)
k_attn(const unsigned* bits, int l, const float* gs, const float* gd, const float* et,
       const float* gs_t4, const int* cat, const void* att, const void* cb,
       float* o) {
    __shared__ __align__(16) float smem[ATTN_SMEM];
    if (bits[0] == BFBITS) attn_body<true>(smem, l, gs, gd, et, gs_t4, cat, att, cb, o);
    else                   attn_body<false>(smem, l, gs, gd, et, gs_t4, cat, att, cb, o);
}

extern "C" void kernel_launch(void* const* d_in, const int* in_sizes, int n_in,
                              void* d_out, int out_size, void* d_ws, size_t ws_size,
                              hipStream_t stream) {
    const void* x     = d_in[0];
    const int*  cat   = (const int*)d_in[1];
    const void* emb   = d_in[2];
    const void* in1W  = d_in[3];
    const void* in1b  = d_in[4];
    const void* ln1g  = d_in[5];
    const void* ln1b  = d_in[6];
    const void* in2W  = d_in[7];
    const void* in2b  = d_in[8];
    const void* ln2g  = d_in[9];
    const void* ln2b  = d_in[10];
    const void* Wl    = d_in[11];
    const void* bl    = d_in[12];
    const void* Wr    = d_in[13];
    const void* br    = d_in[14];
    const void* We    = d_in[15];
    const void* att   = d_in[16];
    const void* cb    = d_in[17];
    const void* pW    = d_in[18];
    const void* pb    = d_in[19];
    const void* lng   = d_in[20];
    const void* lnb   = d_in[21];
    const void* oW    = d_in[22];
    const void* ob    = d_in[23];

    const unsigned* bits = (const unsigned*)ln1g;

    float* ws  = (float*)d_ws;
    float* h     = ws + 16;
    float* gs    = h    + ROWS * DD;     // tmp aliases gs
    float* gd    = gs   + ROWS * DD;
    float* o     = gd   + ROWS * DD;
    float* et    = o    + ROWS * DD;     // L*12*DD
    float* gs_t4 = et   + LL * 12 * DD;  // BB*GT4B
    float* tmp   = gs;

    k_et<<<LL * 12, DD, 0, stream>>>(bits, emb, We, et);
    k_mlp1<<<LBLK, DD, 0, stream>>>(bits, x, in1W, in1b, ln1g, ln1b, tmp);
    // input-MLP linear2 + LN -> h, plus layer-0 gs/gd/gs_t4
    k_linG<<<LBLK, 256, 0, stream>>>(bits, 0, 1, tmp, in2W, 0, in2b, ln2g, ln2b, 0,
                                     Wl, bl, Wr, br, 0, 0, h, gs, gd, gs_t4, oW, ob, d_out);
    for (int l = 0; l < LL; l++) {
        k_attn<<<ROWS, 256, 0, stream>>>(bits, l, gs, gd, et, gs_t4, cat, att, cb, o);
        k_linG<<<LBLK, 256, 0, stream>>>(bits, 1, (l < LL - 1) ? 1 : 0, o,
                                         pW, l * DD * DD, pb, lng, lnb, l * DD,
                                         Wl, bl, Wr, br, (l + 1) * DD * DD, (l + 1) * DD,
                                         h, gs, gd, gs_t4, oW, ob, d_out);
    }
}

// Round 14
// 332.761 us; speedup vs baseline: 1.0937x; 1.0937x over previous
//
#include <hip/hip_runtime.h>
#include <hip/hip_bf16.h>

#define NN 207
#define DD 128
#define LL 4
#define BB 16
#define ROWS (BB*NN)   // 3312
#define RB 8
#define LBLK (ROWS/RB) // 414
#define EPSV 1e-5f
#define SLOPE 0.2f
#define GT4B (32*208*4) // floats per batch in packed-transposed gs

#define BFBITS 0x3F803F80u

// ---------- dtype-flexible load ----------
template<bool BF>
__device__ __forceinline__ float ldin(const void* p, int i) {
    if (BF) {
        unsigned short u = ((const unsigned short*)p)[i];
        return __uint_as_float(((unsigned)u) << 16);
    } else {
        return ((const float*)p)[i];
    }
}

// load float4 worth (4 elems) at float4-index q from a (possibly bf16) array
template<bool BF>
__device__ __forceinline__ float4 ld4(const void* p, int q4) {
    if (BF) {
        uint2 u = ((const uint2*)p)[q4];
        float4 r;
        r.x = __uint_as_float(u.x << 16);
        r.y = __uint_as_float(u.x & 0xFFFF0000u);
        r.z = __uint_as_float(u.y << 16);
        r.w = __uint_as_float(u.y & 0xFFFF0000u);
        return r;
    } else {
        return ((const float4*)p)[q4];
    }
}

// load 32 consecutive weight elements (base multiple of 8) into f32 regs
template<bool BF>
__device__ __forceinline__ void ldw32(const void* W, int base, float* w) {
    if (BF) {
        const uint4* p = (const uint4*)((const unsigned short*)W + base);
#pragma unroll
        for (int q = 0; q < 4; q++) {
            uint4 u = p[q];
            w[q*8+0] = __uint_as_float(u.x << 16);
            w[q*8+1] = __uint_as_float(u.x & 0xFFFF0000u);
            w[q*8+2] = __uint_as_float(u.y << 16);
            w[q*8+3] = __uint_as_float(u.y & 0xFFFF0000u);
            w[q*8+4] = __uint_as_float(u.z << 16);
            w[q*8+5] = __uint_as_float(u.z & 0xFFFF0000u);
            w[q*8+6] = __uint_as_float(u.w << 16);
            w[q*8+7] = __uint_as_float(u.w & 0xFFFF0000u);
        }
    } else {
        const float4* p = (const float4*)((const float*)W + base);
#pragma unroll
        for (int q = 0; q < 8; q++) {
            float4 u = p[q];
            w[q*4+0] = u.x; w[q*4+1] = u.y; w[q*4+2] = u.z; w[q*4+3] = u.w;
        }
    }
}

// dot of one weight row with sh[0..127] (k_et only)
template<bool BF>
__device__ __forceinline__ float rowdot(const void* W, int rowbase, const float* sh) {
    float acc = 0.f;
    if (BF) {
        const uint4* p = (const uint4*)((const unsigned short*)W + rowbase);
#pragma unroll
        for (int q = 0; q < DD / 8; q++) {
            uint4 u = p[q];
            const float* s = sh + q * 8;
            acc += __uint_as_float(u.x << 16)        * s[0];
            acc += __uint_as_float(u.x & 0xFFFF0000u) * s[1];
            acc += __uint_as_float(u.y << 16)        * s[2];
            acc += __uint_as_float(u.y & 0xFFFF0000u) * s[3];
            acc += __uint_as_float(u.z << 16)        * s[4];
            acc += __uint_as_float(u.z & 0xFFFF0000u) * s[5];
            acc += __uint_as_float(u.w << 16)        * s[6];
            acc += __uint_as_float(u.w & 0xFFFF0000u) * s[7];
        }
    } else {
        const float4* p = (const float4*)((const float*)W + rowbase);
#pragma unroll
        for (int q = 0; q < DD / 4; q++) {
            float4 u = p[q];
            const float* s = sh + q * 4;
            acc += u.x * s[0]; acc += u.y * s[1]; acc += u.z * s[2]; acc += u.w * s[3];
        }
    }
    return acc;
}

// ---------- edge tables: et[l][c12][d] ----------
template<bool BF>
__device__ void et_body(float* sh, const void* emb, const void* We, float* et) {
    int l = blockIdx.x / 12, c = blockIdx.x % 12, d = threadIdx.x;
    sh[d] = ldin<BF>(emb, c * DD + d);
    __syncthreads();
    et[(l * 12 + c) * DD + d] = rowdot<BF>(We, l * DD * DD + d * DD, sh);
}
__global__ void k_et(const unsigned* bits, const void* emb, const void* We, float* et) {
    __shared__ __align__(16) float smem[DD];
    if (bits[0] == BFBITS) et_body<true>(smem, emb, We, et);
    else                   et_body<false>(smem, emb, We, et);
}

// ---------- mlp1: Linear(6->D) -> LN -> ReLU -> tmp ----------
template<bool BF>
__device__ void mlp1_body(float* smem, const void* x, const void* W1, const void* b1,
                          const void* g1, const void* bv1, float* tmp) {
    float* s_x   = smem;                 // 48
    float* so    = s_x + 48;             // RB*132
    float* stats = so + RB * 132;        // RB*2
    int r0 = blockIdx.x * RB, d = threadIdx.x;
    if (d < RB * 6) s_x[d] = ldin<BF>(x, r0 * 6 + d);
    __syncthreads();
    float w6[6];
#pragma unroll
    for (int k = 0; k < 6; k++) w6[k] = ldin<BF>(W1, d * 6 + k);
    float b0 = ldin<BF>(b1, d);
#pragma unroll
    for (int rr = 0; rr < RB; rr++) {
        float a = b0;
#pragma unroll
        for (int k = 0; k < 6; k++) a += w6[k] * s_x[rr * 6 + k];
        so[rr * 132 + d] = a;
    }
    __syncthreads();
    int rr2 = d >> 4, l16 = d & 15;
    float s = 0.f, sq = 0.f;
#pragma unroll
    for (int k = 0; k < 8; k++) { float v = so[rr2 * 132 + l16 + 16 * k]; s += v; sq += v * v; }
    s += __shfl_xor(s, 1); s += __shfl_xor(s, 2); s += __shfl_xor(s, 4); s += __shfl_xor(s, 8);
    sq += __shfl_xor(sq, 1); sq += __shfl_xor(sq, 2); sq += __shfl_xor(sq, 4); sq += __shfl_xor(sq, 8);
    if (l16 == 0) {
        float mean = s * (1.f / DD);
        float var = sq * (1.f / DD) - mean * mean;
        stats[rr2 * 2] = mean; stats[rr2 * 2 + 1] = rsqrtf(var + EPSV);
    }
    __syncthreads();
    float gv = ldin<BF>(g1, d), bb = ldin<BF>(bv1, d);
#pragma unroll
    for (int rr = 0; rr < RB; rr++) {
        float v = (so[rr * 132 + d] - stats[rr * 2]) * stats[rr * 2 + 1] * gv + bb;
        tmp[(r0 + rr) * DD + d] = fmaxf(v, 0.f);
    }
}
__global__ void k_mlp1(const unsigned* bits, const void* x, const void* W1, const void* b1,
                       const void* g1, const void* bv1, float* tmp) {
    __shared__ __align__(16) float smem[48 + RB * 132 + RB * 2];
    if (bits[0] == BFBITS) mlp1_body<true>(smem, x, W1, b1, g1, bv1, tmp);
    else                   mlp1_body<false>(smem, x, W1, b1, g1, bv1, tmp);
}

// ---------- fused: linear + LN (+ReLU+res) -> h, then next gs/gd/gs_t4 OR output head ----------
// smem: sh[RB*DD] | so[RB*132] | stats[16] | s_gs[RB*128]
#define LING_SMEM (RB*DD + RB*132 + 16 + RB*128)
template<bool BF>
__device__ void linG_body(float* smem, int epi, int hasNext,
                          const float* __restrict__ in, const void* W, int wOff,
                          const void* bias, const void* g, const void* bv, int dOff,
                          const void* Wl, const void* bl, const void* Wr, const void* br,
                          int nwOff, int nbOff,
                          float* __restrict__ h, float* __restrict__ gs,
                          float* __restrict__ gd, float* __restrict__ gs_t4,
                          const void* oW, const void* ob, void* out) {
    float* sh    = smem;
    float* so    = sh + RB * DD;
    float* stats = so + RB * 132;
    float* s_gs  = stats + 16;
    int r0 = blockIdx.x * RB;
    int t = threadIdx.x, d = t & 127, half = t >> 7;
    // ---- stage input rows into LDS (coalesced float4) ----
    ((float4*)sh)[t] = ((const float4*)(in + (size_t)r0 * DD))[t];
    __syncthreads();
    // ---- phase A: projection linear (rows half*4..half*4+3) ----
    float acc[4];
    float b0 = ldin<BF>(bias, dOff + d);
#pragma unroll
    for (int rr = 0; rr < 4; rr++) acc[rr] = b0;
#pragma unroll
    for (int c = 0; c < 4; c++) {
        float w[32];
        ldw32<BF>(W, wOff + d * DD + c * 32, w);
#pragma unroll
        for (int rr = 0; rr < 4; rr++) {
            const float* s = sh + (half * 4 + rr) * DD + c * 32;
            float a = acc[rr];
#pragma unroll
            for (int k = 0; k < 32; k++) a += s[k] * w[k];
            acc[rr] = a;
        }
    }
#pragma unroll
    for (int rr = 0; rr < 4; rr++) so[(half * 4 + rr) * 132 + d] = acc[rr];
    __syncthreads();
    // ---- LN stats (8 rows x 32 lanes) ----
    int rr2 = t >> 5, l32 = t & 31;
    float s = 0.f, sq = 0.f;
#pragma unroll
    for (int k = 0; k < 4; k++) { float v = so[rr2 * 132 + l32 + 32 * k]; s += v; sq += v * v; }
    s += __shfl_xor(s, 1); s += __shfl_xor(s, 2); s += __shfl_xor(s, 4);
    s += __shfl_xor(s, 8); s += __shfl_xor(s, 16);
    sq += __shfl_xor(sq, 1); sq += __shfl_xor(sq, 2); sq += __shfl_xor(sq, 4);
    sq += __shfl_xor(sq, 8); sq += __shfl_xor(sq, 16);
    if (l32 == 0) {
        float mean = s * (1.f / DD);
        float var = sq * (1.f / DD) - mean * mean;
        stats[rr2 * 2] = mean; stats[rr2 * 2 + 1] = rsqrtf(var + EPSV);
    }
    __syncthreads();
    // ---- epilogue: h_new -> global h AND into sh ----
    float gv = ldin<BF>(g, dOff + d), bb = ldin<BF>(bv, dOff + d);
#pragma unroll
    for (int rr = 0; rr < 4; rr++) {
        int row = half * 4 + rr;
        int rg = r0 + row;
        float v = (so[row * 132 + d] - stats[row * 2]) * stats[row * 2 + 1] * gv + bb;
        float hn;
        if (epi) hn = h[(size_t)rg * DD + d] + fmaxf(v, 0.f);
        else     hn = v;
        h[(size_t)rg * DD + d] = hn;
        sh[row * DD + d] = hn;
    }
    __syncthreads();
    if (!hasNext) {
        // ---- output head ----
        float s0 = 0.f, s1 = 0.f;
#pragma unroll
        for (int k = 0; k < 4; k++) {
            int dd = l32 + 32 * k;
            float hv = sh[rr2 * DD + dd];
            s0 += hv * ldin<BF>(oW, dd);
            s1 += hv * ldin<BF>(oW, DD + dd);
        }
        s0 += __shfl_xor(s0, 1); s0 += __shfl_xor(s0, 2); s0 += __shfl_xor(s0, 4);
        s0 += __shfl_xor(s0, 8); s0 += __shfl_xor(s0, 16);
        s1 += __shfl_xor(s1, 1); s1 += __shfl_xor(s1, 2); s1 += __shfl_xor(s1, 4);
        s1 += __shfl_xor(s1, 8); s1 += __shfl_xor(s1, 16);
        if (l32 == 0) {
            int rg = r0 + rr2;
            float v0 = s0 + ldin<BF>(ob, 0);
            float v1 = s1 + ldin<BF>(ob, 1);
            if (BF) {
                ((__hip_bfloat16*)out)[rg * 2 + 0] = __float2bfloat16(v0);
                ((__hip_bfloat16*)out)[rg * 2 + 1] = __float2bfloat16(v1);
            } else {
                ((float*)out)[rg * 2 + 0] = v0;
                ((float*)out)[rg * 2 + 1] = v1;
            }
        }
        return;
    }
    // ---- phase B: gs/gd for next layer from sh (half -> Wl/Wr) ----
    {
        const void* Wm = half ? Wr : Wl;
        const void* bm = half ? br : bl;
        float acc2[RB];
        float bn = ldin<BF>(bm, nbOff + d);
#pragma unroll
        for (int rr = 0; rr < RB; rr++) acc2[rr] = bn;
#pragma unroll
        for (int c = 0; c < 4; c++) {
            float w[32];
            ldw32<BF>(Wm, nwOff + d * DD + c * 32, w);
#pragma unroll
            for (int rr = 0; rr < RB; rr++) {
                const float* s = sh + rr * DD + c * 32;
                float a = acc2[rr];
#pragma unroll
                for (int k = 0; k < 32; k++) a += s[k] * w[k];
                acc2[rr] = a;
            }
        }
        if (half) {
#pragma unroll
            for (int rr = 0; rr < RB; rr++) gd[(size_t)(r0 + rr) * DD + d] = acc2[rr];
        } else {
#pragma unroll
            for (int rr = 0; rr < RB; rr++) {
                gs[(size_t)(r0 + rr) * DD + d] = acc2[rr];
                s_gs[rr * DD + d] = acc2[rr];
            }
        }
    }
    __syncthreads();
    // ---- gs_t4 write via LDS transpose: lane -> (d4 = t>>3, iL = t&7), i-contiguous ----
    {
        int d4 = t >> 3, iL = t & 7;
        int rg = r0 + iL;
        int bb2 = rg / NN, ii = rg - bb2 * NN;
        float4 v;
        v.x = s_gs[iL * DD + d4 * 4 + 0];
        v.y = s_gs[iL * DD + d4 * 4 + 1];
        v.z = s_gs[iL * DD + d4 * 4 + 2];
        v.w = s_gs[iL * DD + d4 * 4 + 3];
        ((float4*)(gs_t4 + (size_t)bb2 * GT4B))[d4 * 208 + ii] = v;
    }
}
__global__ void k_linG(const unsigned* bits, int epi, int hasNext,
                       const float* in, const void* W, int wOff,
                       const void* bias, const void* g, const void* bv, int dOff,
                       const void* Wl, const void* bl, const void* Wr, const void* br,
                       int nwOff, int nbOff,
                       float* h, float* gs, float* gd, float* gs_t4,
                       const void* oW, const void* ob, void* out) {
    __shared__ __align__(16) float smem[LING_SMEM];
    if (bits[0] == BFBITS)
        linG_body<true>(smem, epi, hasNext, in, W, wOff, bias, g, bv, dOff,
                        Wl, bl, Wr, br, nwOff, nbOff, h, gs, gd, gs_t4, oW, ob, out);
    else
        linG_body<false>(smem, epi, hasNext, in, W, wOff, bias, g, bv, dOff,
                         Wl, bl, Wr, br, nwOff, nbOff, h, gs, gd, gs_t4, oW, ob, out);
}

// ---------- fused attention (1 target per block, 256 thr, XCD-swizzled) ----------
// smem floats: s_ge 12*132 | s_pe 8*212 | s_inv 8 | s_part 128 | s_cat 207
#define ATTN_SMEM (12*132 + 8*212 + 8 + 128 + 207)
template<bool BF>
__device__ void attn_body(float* smem, int l, const float* __restrict__ gs,
                          const float* __restrict__ gd, const float* __restrict__ et,
                          const float* __restrict__ gs_t4, const int* __restrict__ cat,
                          const void* att, const void* cb, float* __restrict__ o) {
    float* s_ge   = smem;                  // 1584
    float* s_pe   = s_ge + 12 * 132;       // 1696
    float* s_inv  = s_pe + 8 * 212;        // 8
    float* s_part = s_inv + 8;             // 128
    int*   s_cat  = (int*)(s_part + 128);  // 207
    int p = blockIdx.x;
    int r = (p & 7) * (ROWS / 8) + (p >> 3);
    int t = threadIdx.x, d = t & 127, seg = t >> 7;
    int b = r / NN, j = r - b * NN;
    for (int idx = t; idx < NN; idx += 256) s_cat[idx] = cat[idx * NN + j];
    for (int idx = t; idx < 12 * DD; idx += 256) {
        int c = idx >> 7, k = idx & 127;
        s_ge[c * 132 + k] = et[l * 12 * DD + idx] + gd[(size_t)r * DD + k];
    }
    __syncthreads();
    const float* gsb = gs + (size_t)b * NN * DD;
    // phase 1: one source per thread; att read from GLOBAL (uniform -> scalar cache)
    if (t < NN) {
        const float4* gt = ((const float4*)(gs_t4 + (size_t)b * GT4B)) + t;
        const float4* ge = (const float4*)(s_ge + s_cat[t] * 132);
        float acc[8];
#pragma unroll
        for (int hh = 0; hh < 8; hh++) acc[hh] = 0.f;
#pragma unroll
        for (int q = 0; q < 32; q++) {
            float4 g4 = gt[q * 208];
            float4 e4 = ge[q];
            float4 a4 = ld4<BF>(att, l * 32 + q);
            float z0 = g4.x + e4.x, z1 = g4.y + e4.y, z2 = g4.z + e4.z, z3 = g4.w + e4.w;
            z0 = fmaxf(z0, SLOPE * z0); z1 = fmaxf(z1, SLOPE * z1);
            z2 = fmaxf(z2, SLOPE * z2); z3 = fmaxf(z3, SLOPE * z3);
            acc[q >> 2] += a4.x * z0 + a4.y * z1 + a4.z * z2 + a4.w * z3;
        }
#pragma unroll
        for (int hh = 0; hh < 8; hh++) s_pe[hh * 212 + t] = acc[hh];
    }
    __syncthreads();
    // phase 2: per-head softmax (threads 0..127)
    if (t < 128) {
        int hh = t >> 4, l16 = t & 15;
        float vals[13]; float mx = -1e30f;
#pragma unroll
        for (int k = 0; k < 13; k++) {
            int i = l16 + 16 * k;
            vals[k] = (i < NN) ? s_pe[hh * 212 + i] : -1e30f;
            mx = fmaxf(mx, vals[k]);
        }
        mx = fmaxf(mx, __shfl_xor(mx, 1)); mx = fmaxf(mx, __shfl_xor(mx, 2));
        mx = fmaxf(mx, __shfl_xor(mx, 4)); mx = fmaxf(mx, __shfl_xor(mx, 8));
        float sum = 0.f;
#pragma unroll
        for (int k = 0; k < 13; k++) {
            int i = l16 + 16 * k;
            float e = (i < NN) ? __expf(vals[k] - mx) : 0.f;
            if (i < 208) s_pe[hh * 212 + i] = e;
            sum += e;
        }
        sum += __shfl_xor(sum, 1); sum += __shfl_xor(sum, 2);
        sum += __shfl_xor(sum, 4); sum += __shfl_xor(sum, 8);
        if (l16 == 0) s_inv[hh] = 1.f / sum;
    }
    __syncthreads();
    // phase 3: o[d] = sum_i e[h(d)][i] * gs[b][i][d], i-range split across seg
    {
        int hh = d >> 4;
        const float* ep = s_pe + hh * 212;
        const float* gp = gsb + d;
        float a0 = 0.f, a1 = 0.f, a2 = 0.f, a3 = 0.f;
        int i = seg * 104;
        int iend = seg ? NN : 104;
        for (; i + 8 <= iend; i += 8) {
            float g0 = gp[(i+0)*DD], g1 = gp[(i+1)*DD], g2 = gp[(i+2)*DD], g3 = gp[(i+3)*DD];
            float g4 = gp[(i+4)*DD], g5 = gp[(i+5)*DD], g6 = gp[(i+6)*DD], g7 = gp[(i+7)*DD];
            a0 = fmaf(ep[i+0], g0, a0); a1 = fmaf(ep[i+1], g1, a1);
            a2 = fmaf(ep[i+2], g2, a2); a3 = fmaf(ep[i+3], g3, a3);
            a0 = fmaf(ep[i+4], g4, a0); a1 = fmaf(ep[i+5], g5, a1);
            a2 = fmaf(ep[i+6], g6, a2); a3 = fmaf(ep[i+7], g7, a3);
        }
        for (; i < iend; i++) a0 = fmaf(ep[i], gp[i * DD], a0);
        float part = a0 + a1 + a2 + a3;
        if (seg) s_part[d] = part;
        __syncthreads();
        if (!seg) o[(size_t)r * DD + d] = (part + s_part[d]) * s_inv[hh] + ldin<BF>(cb, l * DD + d);
    }
}
__global__ void __launch_bounds__(256, 4)
k_attn(const unsigned* bits, int l, const float* gs, const float* gd, const float* et,
       const float* gs_t4, const int* cat, const void* att, const void* cb,
       float* o) {
    __shared__ __align__(16) float smem[ATTN_SMEM];
    if (bits[0] == BFBITS) attn_body<true>(smem, l, gs, gd, et, gs_t4, cat, att, cb, o);
    else                   attn_body<false>(smem, l, gs, gd, et, gs_t4, cat, att, cb, o);
}

extern "C" void kernel_launch(void* const* d_in, const int* in_sizes, int n_in,
                              void* d_out, int out_size, void* d_ws, size_t ws_size,
                              hipStream_t stream) {
    const void* x     = d_in[0];
    const int*  cat   = (const int*)d_in[1];
    const void* emb   = d_in[2];
    const void* in1W  = d_in[3];
    const void* in1b  = d_in[4];
    const void* ln1g  = d_in[5];
    const void* ln1b  = d_in[6];
    const void* in2W  = d_in[7];
    const void* in2b  = d_in[8];
    const void* ln2g  = d_in[9];
    const void* ln2b  = d_in[10];
    const void* Wl    = d_in[11];
    const void* bl    = d_in[12];
    const void* Wr    = d_in[13];
    const void* br    = d_in[14];
    const void* We    = d_in[15];
    const void* att   = d_in[16];
    const void* cb    = d_in[17];
    const void* pW    = d_in[18];
    const void* pb    = d_in[19];
    const void* lng   = d_in[20];
    const void* lnb   = d_in[21];
    const void* oW    = d_in[22];
    const void* ob    = d_in[23];

    const unsigned* bits = (const unsigned*)ln1g;

    float* ws  = (float*)d_ws;
    float* h     = ws + 16;
    float* gs    = h    + ROWS * DD;     // tmp aliases gs
    float* gd    = gs   + ROWS * DD;
    float* o     = gd   + ROWS * DD;
    float* et    = o    + ROWS * DD;     // L*12*DD
    float* gs_t4 = et   + LL * 12 * DD;  // BB*GT4B
    float* tmp   = gs;

    k_et<<<LL * 12, DD, 0, stream>>>(bits, emb, We, et);
    k_mlp1<<<LBLK, DD, 0, stream>>>(bits, x, in1W, in1b, ln1g, ln1b, tmp);
    // input-MLP linear2 + LN -> h, plus layer-0 gs/gd/gs_t4
    k_linG<<<LBLK, 256, 0, stream>>>(bits, 0, 1, tmp, in2W, 0, in2b, ln2g, ln2b, 0,
                                     Wl, bl, Wr, br, 0, 0, h, gs, gd, gs_t4, oW, ob, d_out);
    for (int l = 0; l < LL; l++) {
        k_attn<<<ROWS, 256, 0, stream>>>(bits, l, gs, gd, et, gs_t4, cat, att, cb, o);
        k_linG<<<LBLK, 256, 0, stream>>>(bits, 1, (l < LL - 1) ? 1 : 0, o,
                                         pW, l * DD * DD, pb, lng, lnb, l * DD,
                                         Wl, bl, Wr, br, (l + 1) * DD * DD, (l + 1) * DD,
                                         h, gs, gd, gs_t4, oW, ob, d_out);
    }
}